// Round 12
// baseline (169.154 us; speedup 1.0000x reference)
//
#include <hip/hip_runtime.h>
#include <hip/hip_bf16.h>
#include <hip/hip_fp16.h>
#include <math.h>

#define C_   256
#define G_   4
#define P_   9
#define GC_  64
#define H_   96
#define W_   96
#define N_   2
#define HW_  (H_*W_)          // 9216
#define CHW_ (C_*H_*W_)       // 2359296
#define OMC  108              // G*P*3
#define OMR  112              // padded rows of om_w bf16 copy
#define TILE 16               // pixels along w per block (main)
#define NBW  (W_/TILE)        // 6
#define NBLK (N_*H_*NBW)      // 1152 main tiles
#define NCONV 768             // prep conv blocks: N*(H/4)*(C/16)
#define NOMW  16              // prep tail blocks converting om_w
#define CH_ST 628             // shorts per channel in prep LDS
#define ROW_ST 104            // shorts per staged row
#define FEATB_ST 264          // shorts per pixel row in main
#define OMS_ST 114
#define TBUF_ST 17

typedef __attribute__((ext_vector_type(8))) short bf16x8;
typedef __attribute__((ext_vector_type(4))) float f32x4;

__device__ __forceinline__ short f2bf(float f) {
    __hip_bfloat16 h = __float2bfloat16(f);
    return *reinterpret_cast<short*>(&h);
}
__device__ __forceinline__ unsigned short f2bfu(float f) {
    return (unsigned short)f2bf(f);
}
__device__ __forceinline__ float bflo(unsigned u) {
    union { unsigned q; float f; } v; v.q = u << 16; return v.f;
}
__device__ __forceinline__ float bfhi(unsigned u) {
    union { unsigned q; float f; } v; v.q = u & 0xffff0000u; return v.f;
}

// ws layout (bytes):
//   [0)      partials: NCONV*2 floats (6144 B), deterministic per-block sums
//   [8192)   counter: 1 uint (memset to 0 each call)
//   [12288)  stats: 4 floats {mean0, rstd0, mean1, rstd1}
//   [16384)  omwb: 112*256 bf16 (57344 B)
//   [81920)  xn  bf16 NHWC (9.44 MB)
//   [+)      ctx bf16 NHWC (9.44 MB)
// Determinism: the only atomic is an INTEGER done-counter; the final stats
// reduction runs in exactly one block in a fixed order -> bitwise-identical
// stats every call (float atomicAdd ordering broke R7 — never again).

// ---------------- K0: prep — conv blocks + last-block stats + omwb tail ----------------
__global__ __launch_bounds__(256) void prep_kernel(
    const float* __restrict__ x, const float* __restrict__ dw_w,
    const float* __restrict__ dw_b, const float* __restrict__ om_w,
    __hip_bfloat16* __restrict__ xn, __hip_bfloat16* __restrict__ ctx,
    __hip_bfloat16* __restrict__ omwb, float* __restrict__ partials,
    unsigned* __restrict__ counter, float* __restrict__ stats)
{
    const int b = blockIdx.x;
    const int tid = threadIdx.x;

    if (b >= NCONV) {
        // ---- om_w f32[108][256] -> omwb bf16[112][256] (rows 108..111 zero) ----
        const int bb = b - NCONV;                    // 0..15
        const float4* src = (const float4*)om_w;     // 6912 float4 valid
        ushort4* dst = (ushort4*)omwb;               // 7168 ushort4 total
#pragma unroll
        for (int it = 0; it < 2; ++it) {
            int i = tid + it * 256;
            if (i < 448) {
                int fi = bb * 448 + i;
                float4 v = (fi < 6912) ? src[fi] : make_float4(0.f, 0.f, 0.f, 0.f);
                ushort4 u;
                u.x = f2bfu(v.x); u.y = f2bfu(v.y);
                u.z = f2bfu(v.z); u.w = f2bfu(v.w);
                dst[fi] = u;
            }
        }
        return;
    }

    // ---- conv block: 16 channels x 4 output rows (R11-validated) ----
    __shared__ short xs[16 * CH_ST];   // 20096 B
    __shared__ float red[8];
    __shared__ int lastFlag;
    const int xcd = b & 7, q = b >> 3;           // q in [0,96)
    const int nh4 = xcd * 6 + (q >> 4);          // row-quad [0,48)
    const int ct = q & 15;                       // channel group [0,16)
    const int n = nh4 / 24, h0 = (nh4 % 24) * 4;
    const int c0 = ct * 16;

    if (tid < 96) {
        int c = tid / 6, r = tid % 6;
        unsigned* zp = (unsigned*)xs;
        zp[c * (CH_ST / 2) + r * (ROW_ST / 2) + 1]  = 0u;
        zp[c * (CH_ST / 2) + r * (ROW_ST / 2) + 50] = 0u;
    }
    {
        ushort4* xsv = (ushort4*)xs;
#pragma unroll
        for (int it = 0; it < 9; ++it) {
            int idx = tid + it * 256;            // 0..2303
            int row = idx / 24;
            int col4 = idx % 24;
            int c = row / 6, r = row % 6;
            int gy = h0 - 1 + r;
            ushort4 u = make_ushort4(0, 0, 0, 0);
            if (gy >= 0 && gy < H_) {
                float4 v = *(const float4*)&x[(size_t)(n * C_ + c0 + c) * HW_ + gy * W_ + col4 * 4];
                u.x = f2bfu(v.x); u.y = f2bfu(v.y);
                u.z = f2bfu(v.z); u.w = f2bfu(v.w);
            }
            xsv[c * (CH_ST / 4) + r * (ROW_ST / 4) + 1 + col4] = u;
        }
    }
    __syncthreads();

    const int c = tid & 15;
    const int slot = tid >> 4;
    const int jr = slot >> 3;
    const int ws = slot & 7;
    const int W0 = ws * 12;
    float wgt[9];
#pragma unroll
    for (int kq = 0; kq < 9; ++kq) wgt[kq] = dw_w[(c0 + c) * 9 + kq];
    const float bias = dw_b[c0 + c];

    float s1 = 0.0f, s2 = 0.0f;
#pragma unroll
    for (int jj = 0; jj < 2; ++jj) {
        const int j = jr * 2 + jj;
        float acc[12];
#pragma unroll
        for (int px = 0; px < 12; ++px) acc[px] = bias;
        float xnv[12];
#pragma unroll
        for (int r3 = 0; r3 < 3; ++r3) {
            const unsigned* rp = (const unsigned*)xs
                               + c * (CH_ST / 2) + (j + r3) * (ROW_ST / 2) + 6 * ws + 1;
            float vals[16];
#pragma unroll
            for (int i = 0; i < 8; ++i) {
                unsigned u = rp[i];
                vals[2 * i]     = bflo(u);
                vals[2 * i + 1] = bfhi(u);
            }
            const float w0v = wgt[r3 * 3 + 0], w1v = wgt[r3 * 3 + 1], w2v = wgt[r3 * 3 + 2];
#pragma unroll
            for (int px = 0; px < 12; ++px)
                acc[px] += w0v * vals[px + 1] + w1v * vals[px + 2] + w2v * vals[px + 3];
            if (r3 == 1) {
#pragma unroll
                for (int px = 0; px < 12; ++px) xnv[px] = vals[px + 2];
            }
        }
        const int gh = h0 + j;
        __hip_bfloat16* cb = ctx + ((size_t)(n * H_ + gh) * W_ + W0) * C_ + c0 + c;
        __hip_bfloat16* xb = xn  + ((size_t)(n * H_ + gh) * W_ + W0) * C_ + c0 + c;
#pragma unroll
        for (int px = 0; px < 12; ++px) {
            float v = acc[px];
            s1 += v; s2 += v * v;
            cb[px * C_] = __float2bfloat16(v);
            xb[px * C_] = __float2bfloat16(xnv[px]);
        }
    }
#pragma unroll
    for (int off = 32; off; off >>= 1) {
        s1 += __shfl_down(s1, off, 64);
        s2 += __shfl_down(s2, off, 64);
    }
    const int lane = tid & 63, wv = tid >> 6;
    if (lane == 0) { red[wv] = s1; red[4 + wv] = s2; }
    __syncthreads();
    if (tid == 0) {
        partials[b * 2 + 0] = red[0] + red[1] + red[2] + red[3];
        partials[b * 2 + 1] = red[4] + red[5] + red[6] + red[7];
        __threadfence();                                   // release partials
        unsigned done = atomicAdd(counter, 1u);            // integer atomic: exact
        lastFlag = (done == NCONV - 1) ? 1 : 0;
    }
    __syncthreads();

    // ---- last conv block reduces all partials in fixed order (deterministic) ----
    if (lastFlag) {
        __threadfence();                                   // acquire partials
        float a0 = 0, b0 = 0, a1 = 0, b1 = 0;
#pragma unroll
        for (int it = 0; it < 3; ++it) {
            int i = tid + it * 256;                        // conv block id [0,768)
            float p1 = partials[i * 2 + 0], p2 = partials[i * 2 + 1];
            if (((i & 7) >> 2) == 0) { a0 += p1; b0 += p2; }   // xcd<4 -> n=0
            else                     { a1 += p1; b1 += p2; }
        }
#pragma unroll
        for (int off = 32; off; off >>= 1) {
            a0 += __shfl_down(a0, off, 64); b0 += __shfl_down(b0, off, 64);
            a1 += __shfl_down(a1, off, 64); b1 += __shfl_down(b1, off, 64);
        }
        __shared__ float sred[4][4];
        if (lane == 0) { sred[wv][0] = a0; sred[wv][1] = b0; sred[wv][2] = a1; sred[wv][3] = b1; }
        __syncthreads();
        if (tid == 0) {
            float A0 = sred[0][0] + sred[1][0] + sred[2][0] + sred[3][0];
            float B0 = sred[0][1] + sred[1][1] + sred[2][1] + sred[3][1];
            float A1 = sred[0][2] + sred[1][2] + sred[2][2] + sred[3][2];
            float B1 = sred[0][3] + sred[1][3] + sred[2][3] + sred[3][3];
            float m0 = A0 * (1.0f / (float)CHW_);
            float v0 = B0 * (1.0f / (float)CHW_) - m0 * m0;
            float m1 = A1 * (1.0f / (float)CHW_);
            float v1 = B1 * (1.0f / (float)CHW_) - m1 * m1;
            stats[0] = m0; stats[1] = rsqrtf(v0 + 1e-5f);
            stats[2] = m1; stats[3] = rsqrtf(v1 + 1e-5f);
        }
    }
}

// ---------------- K1: norm+gelu -> MFMA om matmul -> softmax -> table -> sampling ----------------
// (byte-identical to the R10/R11-validated main_kernel)
__global__ __launch_bounds__(256, 5) void main_kernel(
    const __hip_bfloat16* __restrict__ xn, const float* __restrict__ unc,
    const __hip_bfloat16* __restrict__ ctx, const float* __restrict__ stats,
    const float* __restrict__ gn_w, const float* __restrict__ gn_b,
    const __hip_bfloat16* __restrict__ omwb, const float* __restrict__ om_b,
    float* __restrict__ out)
{
    // overlay plan (time-disjoint):
    //   [0,8448)       featb  short[16][264]    (Phase B->C)
    //   [0,4608)       tidx   uint2[576]        (D2->E)
    //   [4608,13824)   twt    float4[576]       (D2->E)
    //   [13824,21120)  oms    f32[16][114]      (C->D2)
    //   [13824,31232)  tbuf   f32[256][17]      (E->F)
    __shared__ __align__(16) char smem[31232];
    short* featb  = (short*)smem;
    uint2* tidx   = (uint2*)smem;
    float4* twt   = (float4*)(smem + 4608);
    float* oms    = (float*)(smem + 13824);
    float* tbuf   = (float*)(smem + 13824);

    const int tid = threadIdx.x;
    const int b = blockIdx.x;
    const int xcd = b & 7, bidx = b >> 3;
    const int tile = xcd * (NBLK / 8) + bidx;   // xcd owns contiguous rows -> L2 halo reuse
    const int n = tile / (H_ * NBW);
    const int rem = tile % (H_ * NBW);
    const int h = rem / NBW;
    const int w0 = (rem % NBW) * TILE;

    // ---- Phase B: ctx load + groupnorm + exact GELU -> feat bf16 (thread = channel) ----
    {
        const int c = tid;
        const float mean = stats[n * 2 + 0];
        const float rstd = stats[n * 2 + 1];
        const float gw = gn_w[c], gb = gn_b[c];
        const __hip_bfloat16* cb = ctx + ((size_t)(n * H_ + h) * W_ + w0) * C_ + c;
#pragma unroll
        for (int j = 0; j < TILE; ++j) {
            float v = __bfloat162float(cb[j * C_]);
            float f = (v - mean) * rstd * gw + gb;
            f = 0.5f * f * (1.0f + erff(f * 0.70710678118654752f));
            featb[j * FEATB_ST + c] = f2bf(f);
        }
    }
    __syncthreads();

    // ---- Phase C: om = feat @ om_w.T + om_b via MFMA 16x16x32 bf16 ----
    {
        const int wv = tid >> 6, lane = tid & 63;
        const int mrow = lane & 15, quad = lane >> 4;
        const short* fb  = featb + mrow * FEATB_ST;
        const short* wb0 = (const short*)omwb + (wv * 16 + mrow) * 256;
        const short* wb1 = (const short*)omwb + ((wv + 4) * 16 + mrow) * 256;
        f32x4 acc0 = {0.f, 0.f, 0.f, 0.f}, acc1 = {0.f, 0.f, 0.f, 0.f};
#pragma unroll
        for (int ks = 0; ks < 8; ++ks) {
            const int k = ks * 32 + quad * 8;
            bf16x8 a  = *(const bf16x8*)(fb + k);
            bf16x8 b0 = *(const bf16x8*)(wb0 + k);
            acc0 = __builtin_amdgcn_mfma_f32_16x16x32_bf16(a, b0, acc0, 0, 0, 0);
            if (wv < 3) {
                bf16x8 b1 = *(const bf16x8*)(wb1 + k);
                acc1 = __builtin_amdgcn_mfma_f32_16x16x32_bf16(a, b1, acc1, 0, 0, 0);
            }
        }
        const int j0 = wv * 16 + mrow;
        const float ob0 = om_b[j0];
#pragma unroll
        for (int rg = 0; rg < 4; ++rg)
            oms[(quad * 4 + rg) * OMS_ST + j0] = acc0[rg] + ob0;
        if (wv < 3) {
            const int j1 = (wv + 4) * 16 + mrow;
            if (j1 < OMC) {
                const float ob1 = om_b[j1];
#pragma unroll
                for (int rg = 0; rg < 4; ++rg)
                    oms[(quad * 4 + rg) * OMS_ST + j1] = acc1[rg] + ob1;
            }
        }
    }
    __syncthreads();

    // ---- Phase D1: softmax over P per (pixel, group) * uncertainty ----
    if (tid < TILE * G_) {
        int pix = tid >> 2, g = tid & 3;
        float* m = &oms[pix * OMS_ST + G_ * P_ * 2 + g * P_];
        float mx = m[0];
#pragma unroll
        for (int p = 1; p < P_; ++p) mx = fmaxf(mx, m[p]);
        float e[P_], s = 0.0f;
#pragma unroll
        for (int p = 0; p < P_; ++p) { e[p] = expf(m[p] - mx); s += e[p]; }
        float u = unc[(n * H_ + h) * W_ + w0 + pix];
        float inv = u / s;
#pragma unroll
        for (int p = 0; p < P_; ++p) m[p] = e[p] * inv;
    }
    __syncthreads();

    // ---- Phase D2: build tap table (SoA: packed u16 pixel indices + f32 weights) ----
    for (int e = tid; e < TILE * G_ * P_; e += 256) {   // 576 entries
        int pix = e / (G_ * P_);
        int rr = e - pix * (G_ * P_);
        int g = rr / P_, p = rr - g * P_;
        const float* po = &oms[pix * OMS_ST];
        float ox = po[(g * P_ + p) * 2 + 0];
        float oy = po[(g * P_ + p) * 2 + 1];
        float mk = po[G_ * P_ * 2 + g * P_ + p];
        float sx = (float)(w0 + pix + p / 3) + ox;
        float sy = (float)(h + p % 3) + oy;
        float x0f = floorf(sx), y0f = floorf(sy);
        float wx = sx - x0f, wy = sy - y0f;
        int x0 = (int)x0f - 1, y0 = (int)y0f - 1;       // top-left tap, unpadded
        float fy0 = (y0 >= 0 && y0 < H_) ? 1.0f : 0.0f;
        float fy1 = (y0 + 1 >= 0 && y0 + 1 < H_) ? 1.0f : 0.0f;
        float fx0 = (x0 >= 0 && x0 < W_) ? 1.0f : 0.0f;
        float fx1 = (x0 + 1 >= 0 && x0 + 1 < W_) ? 1.0f : 0.0f;
        int y0c = min(max(y0, 0), H_ - 1), y1c = min(max(y0 + 1, 0), H_ - 1);
        int x0c = min(max(x0, 0), W_ - 1), x1c = min(max(x0 + 1, 0), W_ - 1);
        unsigned i00 = (unsigned)(y0c * W_ + x0c), i01 = (unsigned)(y0c * W_ + x1c);
        unsigned i10 = (unsigned)(y1c * W_ + x0c), i11 = (unsigned)(y1c * W_ + x1c);
        tidx[e] = make_uint2(i00 | (i01 << 16), i10 | (i11 << 16));
        twt[e] = make_float4((1.0f - wy) * (1.0f - wx) * mk * fy0 * fx0,
                             (1.0f - wy) * wx * mk * fy0 * fx1,
                             wy * (1.0f - wx) * mk * fy1 * fx0,
                             wy * wx * mk * fy1 * fx1);
    }
    __syncthreads();

    // ---- Phase E: sampling; wave=group, lane=channel; coalesced NHWC taps ----
    {
        const int g = tid >> 6;
        const int lane = tid & 63;
        const __hip_bfloat16* xg = xn + (size_t)n * HW_ * C_ + g * GC_ + lane;
#pragma unroll 1
        for (int pix = 0; pix < TILE; ++pix) {
            const int te = pix * (G_ * P_) + g * P_;
            float acc = 0.0f;
#pragma unroll
            for (int p = 0; p < P_; ++p) {
                uint2 bi = tidx[te + p];
                float4 wt = twt[te + p];
                acc += wt.x * __bfloat162float(xg[(bi.x & 0xffffu) << 8])
                     + wt.y * __bfloat162float(xg[(bi.x >> 16) << 8])
                     + wt.z * __bfloat162float(xg[(bi.y & 0xffffu) << 8])
                     + wt.w * __bfloat162float(xg[(bi.y >> 16) << 8]);
            }
            tbuf[(g * GC_ + lane) * TBUF_ST + pix] = acc;
        }
    }
    __syncthreads();

    // ---- Phase F: full-line coalesced stores ----
    {
        const int px = tid & 15, c0 = tid >> 4;
        float* op = out + (size_t)n * CHW_ + (size_t)h * W_ + w0 + px;
#pragma unroll
        for (int k = 0; k < 16; ++k) {
            int c = c0 * 16 + k;
            op[(size_t)c * HW_] = tbuf[c * TBUF_ST + px];
        }
    }
}

extern "C" void kernel_launch(void* const* d_in, const int* in_sizes, int n_in,
                              void* d_out, int out_size, void* d_ws, size_t ws_size,
                              hipStream_t stream)
{
    const float* x    = (const float*)d_in[0];
    const float* unc  = (const float*)d_in[1];
    const float* dw_w = (const float*)d_in[2];
    const float* dw_b = (const float*)d_in[3];
    const float* gn_w = (const float*)d_in[4];
    const float* gn_b = (const float*)d_in[5];
    const float* om_w = (const float*)d_in[6];
    const float* om_b = (const float*)d_in[7];
    float* out = (float*)d_out;

    float* partials      = (float*)d_ws;
    unsigned* counter    = (unsigned*)((char*)d_ws + 8192);
    float* stats         = (float*)((char*)d_ws + 12288);
    __hip_bfloat16* omwb = (__hip_bfloat16*)((char*)d_ws + 16384);
    __hip_bfloat16* xn   = (__hip_bfloat16*)((char*)d_ws + 81920);
    __hip_bfloat16* ctx  = xn + (size_t)N_ * HW_ * C_;

    hipMemsetAsync(counter, 0, 4, stream);
    prep_kernel<<<NCONV + NOMW, 256, 0, stream>>>(x, dw_w, dw_b, om_w, xn, ctx,
                                                  omwb, partials, counter, stats);
    main_kernel<<<NBLK, 256, 0, stream>>>(xn, unc, ctx, stats,
                                          gn_w, gn_b, omwb, om_b, out);
}